// Round 3
// baseline (2372.556 us; speedup 1.0000x reference)
//
#include <hip/hip_runtime.h>
#include <hip/hip_bf16.h>
#include <hip/hip_fp8.h>
#include <cstdint>
#include <cstddef>

// VanillaRNN: h_{t+1} = tanh(x_t @ Whx + h_t @ Whh + bh), p = h_T @ Wph + bp
// B=256, T=1024, D=64, H=512, C=10.
//
// R11 vs R10 (1987us, regressed vs R8 1713us):
//  R10's barrier-free design was right; implementation wrong:
//   (a) acquire-per-region => 7x lgkmcnt(0) drains/step killed ds_read->MFMA
//       pipelining (MfmaUtil 51%->44% on-CU);
//   (b) setprio(1) held through spin loops => priority inversion vs epilogue;
//   (c) 8-way BODY switch => ~8x K-loop code, I$ thrash.
//  R11 fixes:
//   * own region first (8-case switch, 2 K-steps each), then ONE gate/step:
//     relaxed volatile poll of all 8 flags (broadcast ds_read) + min-reduce;
//     producer RELEASE already guarantees LDS visibility => no acquire fence,
//     just sched_barrier(0) to pin subsequent ds_reads below the gate.
//   * remaining 14 K-steps in fixed order with wave-uniform skip branches
//     (if (w != r)) — no code replication.
//   * setprio(1) only inside MFMA clusters; prio 0 while spinning/epilogue.
//   * triple-buffered h tile (skew <= 1 step), flags in LDS.
// Fallback (ws < 256MiB): R2 kernel verbatim.

#define T_SEQ   1024
#define D_IN    64
#define H_DIM   512
#define NB      16
#define NBLK    16
#define NTW     4            // N-tiles (16 cols) per wave; wave owns 64 cols
#define KS_F16  10           // f16 K-steps: h[0,320)
#define KS_REG8 2            // fp8 K-steps with reg weights: h[320,384)
#define KS_LDS8 4            // fp8 K-steps with LDS weights: h[384,512)
#define HSPLIT  320          // h cols >= HSPLIT stored fp8
#define APITCH  848          // bytes per A row: 640 f16 + 192 fp8 + 16 pad
#define FP8OFF  640
#define ABUF3   (3 * NB * APITCH)                 // 40704 (triple buffer)
#define WWAVE_BYTES (KS_LDS8 * 2 * 1024)          // 8192
#define WLDS_BYTES (8 * WWAVE_BYTES)              // 65536
#define WLDS_OFF  ABUF3
#define FLAGS_OFF (ABUF3 + WLDS_BYTES)            // 106240 (16B aligned)
#define SMEM_TOTAL (FLAGS_OFF + 64)               // 106304
#define WSCALE  256.0f
#define HSCALE  128.0f
#define UNSCALE (1.0f / 32768.0f)
#define U_BYTES ((size_t)T_SEQ * NBLK * 512 * 32) // 268435456 (f16 U, all t)
#define TTP     64           // t-steps per precompute block (grid 16x16)

typedef __attribute__((ext_vector_type(8))) short  short8;
typedef __attribute__((ext_vector_type(4))) short  short4v;
typedef __attribute__((ext_vector_type(4))) float  f32x4;
typedef __attribute__((ext_vector_type(4))) unsigned int uint4v;
typedef __attribute__((ext_vector_type(2))) unsigned int uint2v;

static __device__ __forceinline__ short f16b(float v) {
  return __builtin_bit_cast(short, (_Float16)v);
}
static __device__ __forceinline__ short bf16b(float v) {
  return __builtin_bit_cast(short, __float2bfloat16(v));
}
static __device__ __forceinline__ float f16f(unsigned short u) {
  return (float)__builtin_bit_cast(_Float16, (short)u);
}
static __device__ __forceinline__ unsigned int pk2h(float a, float b) {
#if defined(__has_builtin) && __has_builtin(__builtin_amdgcn_cvt_pkrtz)
  return __builtin_bit_cast(unsigned int, __builtin_amdgcn_cvt_pkrtz(a, b));
#else
  return (unsigned int)(unsigned short)f16b(a) |
         ((unsigned int)(unsigned short)f16b(b) << 16);
#endif
}
static __device__ __forceinline__ float fast_tanh(float x) {
  x = fminf(20.f, fmaxf(-20.f, x));
  const float t = __builtin_amdgcn_exp2f(x * 2.885390081777927f); // 2*log2(e)
  return (t - 1.f) * __builtin_amdgcn_rcpf(t + 1.f);
}
static __device__ __forceinline__ unsigned char f32_to_fp8(float v) {
#if defined(__has_builtin) && __has_builtin(__builtin_amdgcn_cvt_pk_fp8_f32)
  const int r = __builtin_amdgcn_cvt_pk_fp8_f32(v, v, 0, false);
  return (unsigned char)(r & 0xff);
#else
  __hip_fp8_e4m3 f(v);
  return (unsigned char)f.__x;
#endif
}
static __device__ __forceinline__ unsigned int pk4fp8(float a, float b, float c, float d) {
#if defined(__has_builtin) && __has_builtin(__builtin_amdgcn_cvt_pk_fp8_f32)
  int r = __builtin_amdgcn_cvt_pk_fp8_f32(a, b, 0, false);
  r = __builtin_amdgcn_cvt_pk_fp8_f32(c, d, r, true);
  return (unsigned int)r;
#else
  return (unsigned int)f32_to_fp8(a) | ((unsigned int)f32_to_fp8(b) << 8) |
         ((unsigned int)f32_to_fp8(c) << 16) | ((unsigned int)f32_to_fp8(d) << 24);
#endif
}
static __device__ __forceinline__ float fp8_to_f32(unsigned char b) {
  __hip_fp8_e4m3 f;
  f.__x = (__hip_fp8_storage_t)b;
  return (float)f;
}

// ============================ precompute: U = x@Whx + bh (R8 verbatim) =======
__global__ __launch_bounds__(512, 2)
void rnn_u_precompute(const float* __restrict__ x, const float* __restrict__ Whx,
                      const float* __restrict__ bh, char* __restrict__ U)
{
  const int tid  = threadIdx.x;
  const int lane = tid & 63;
  const int w    = tid >> 6;
  const int n16  = lane & 15;
  const int kq   = lane >> 4;
  const int wg   = blockIdx.x;
  const int cwave = w * 64;

  short8 wa[2][NTW];
  #pragma unroll
  for (int s = 0; s < 2; ++s) {
    #pragma unroll
    for (int nt = 0; nt < NTW; ++nt) {
      const int c = cwave + nt * 16 + n16;
      short8 f;
      #pragma unroll
      for (int j = 0; j < 8; ++j)
        f[j] = f16b(Whx[(size_t)(s * 32 + kq * 8 + j) * H_DIM + c]);
      wa[s][nt] = f;
    }
  }
  f32x4 bb[NTW];
  #pragma unroll
  for (int nt = 0; nt < NTW; ++nt) {
    #pragma unroll
    for (int i = 0; i < 4; ++i) bb[nt][i] = bh[cwave + nt * 16 + kq * 4 + i];
  }

  const int b = wg * NB + n16;
  const float* pxb = x + (size_t)b * T_SEQ * D_IN + kq * 8;
  const int t0 = blockIdx.y * TTP;

  f32x4 c0, c1, c2, c3;
  {
    const float* p = pxb + (size_t)t0 * D_IN;
    c0 = *(const f32x4*)p;        c1 = *(const f32x4*)(p + 4);
    c2 = *(const f32x4*)(p + 32); c3 = *(const f32x4*)(p + 36);
  }

  for (int tt = 0; tt < TTP; ++tt) {
    const int t = t0 + tt;
    f32x4 n0, n1, n2, n3;
    if (tt + 1 < TTP) {
      const float* p = pxb + (size_t)(t + 1) * D_IN;
      n0 = *(const f32x4*)p;        n1 = *(const f32x4*)(p + 4);
      n2 = *(const f32x4*)(p + 32); n3 = *(const f32x4*)(p + 36);
    }
    short8 xb0, xb1;
    xb0[0]=f16b(c0.x); xb0[1]=f16b(c0.y); xb0[2]=f16b(c0.z); xb0[3]=f16b(c0.w);
    xb0[4]=f16b(c1.x); xb0[5]=f16b(c1.y); xb0[6]=f16b(c1.z); xb0[7]=f16b(c1.w);
    xb1[0]=f16b(c2.x); xb1[1]=f16b(c2.y); xb1[2]=f16b(c2.z); xb1[3]=f16b(c2.w);
    xb1[4]=f16b(c3.x); xb1[5]=f16b(c3.y); xb1[6]=f16b(c3.z); xb1[7]=f16b(c3.w);

    f32x4 D[NTW];
    #pragma unroll
    for (int nt = 0; nt < NTW; ++nt) {
      D[nt] = bb[nt];
      D[nt] = __builtin_amdgcn_mfma_f32_16x16x32_f16(wa[0][nt], xb0, D[nt], 0, 0, 0);
      D[nt] = __builtin_amdgcn_mfma_f32_16x16x32_f16(wa[1][nt], xb1, D[nt], 0, 0, 0);
    }
    uint4v o0, o1;
    o0.x = pk2h(D[0][0], D[0][1]); o0.y = pk2h(D[0][2], D[0][3]);
    o0.z = pk2h(D[1][0], D[1][1]); o0.w = pk2h(D[1][2], D[1][3]);
    o1.x = pk2h(D[2][0], D[2][1]); o1.y = pk2h(D[2][2], D[2][3]);
    o1.z = pk2h(D[3][0], D[3][1]); o1.w = pk2h(D[3][2], D[3][3]);
    char* dst = U + (((size_t)t * NBLK + wg) * 512 + tid) * 32;
    *(uint4v*)dst = o0;
    *(uint4v*)(dst + 16) = o1;

    c0 = n0; c1 = n1; c2 = n2; c3 = n3;
  }
}

// ====================== main recurrence: barrier-free, one gate/step =========

// one f16 K-step (s compile-time)
#define MF16(sA) do {                                                          \
    const short8 a_ = *(const short8*)(Ac + n16 * APITCH + (sA) * 64 + kq * 16);\
    C[0] = __builtin_amdgcn_mfma_f32_16x16x32_f16(wr[sA][0], a_, C[0], 0, 0, 0);\
    C[1] = __builtin_amdgcn_mfma_f32_16x16x32_f16(wr[sA][1], a_, C[1], 0, 0, 0);\
    C[2] = __builtin_amdgcn_mfma_f32_16x16x32_f16(wr[sA][2], a_, C[2], 0, 0, 0);\
    C[3] = __builtin_amdgcn_mfma_f32_16x16x32_f16(wr[sA][3], a_, C[3], 0, 0, 0);\
  } while (0)

// one fp8 K-step, reg weights (s8 compile-time)
#define MR8(s8) do {                                                           \
    const long long h8_ = *(const long long*)(Ac + n16 * APITCH + FP8OFF + (s8) * 32 + kq * 8); \
    C2[0] = __builtin_amdgcn_mfma_f32_16x16x32_fp8_fp8(wf8[s8][0], h8_, C2[0], 0, 0, 0); \
    C2[1] = __builtin_amdgcn_mfma_f32_16x16x32_fp8_fp8(wf8[s8][1], h8_, C2[1], 0, 0, 0); \
    C2[2] = __builtin_amdgcn_mfma_f32_16x16x32_fp8_fp8(wf8[s8][2], h8_, C2[2], 0, 0, 0); \
    C2[3] = __builtin_amdgcn_mfma_f32_16x16x32_fp8_fp8(wf8[s8][3], h8_, C2[3], 0, 0, 0); \
  } while (0)

// one fp8 K-step, LDS weights (sl compile-time)
#define ML8(sl) do {                                                           \
    const long long h8_ = *(const long long*)(Ac + n16 * APITCH + FP8OFF + (KS_REG8 + (sl)) * 32 + kq * 8); \
    const uint4v q0_ = *(const uint4v*)(Wlw + (size_t)((sl) * 2 + 0) * 1024 + lane * 16); \
    const uint4v q1_ = *(const uint4v*)(Wlw + (size_t)((sl) * 2 + 1) * 1024 + lane * 16); \
    const long long w0_ = (long long)(((unsigned long long)q0_.y << 32) | q0_.x); \
    const long long w1_ = (long long)(((unsigned long long)q0_.w << 32) | q0_.z); \
    const long long w2_ = (long long)(((unsigned long long)q1_.y << 32) | q1_.x); \
    const long long w3_ = (long long)(((unsigned long long)q1_.w << 32) | q1_.z); \
    C2[0] = __builtin_amdgcn_mfma_f32_16x16x32_fp8_fp8(w0_, h8_, C2[0], 0, 0, 0); \
    C2[1] = __builtin_amdgcn_mfma_f32_16x16x32_fp8_fp8(w1_, h8_, C2[1], 0, 0, 0); \
    C2[2] = __builtin_amdgcn_mfma_f32_16x16x32_fp8_fp8(w2_, h8_, C2[2], 0, 0, 0); \
    C2[3] = __builtin_amdgcn_mfma_f32_16x16x32_fp8_fp8(w3_, h8_, C2[3], 0, 0, 0); \
  } while (0)

// ONE gate per step: relaxed poll of all 8 flags until min >= t.
// Producer RELEASE (lgkmcnt(0) before flag ds_write) guarantees LDS
// visibility when the flag value is observed; no acquire fence needed.
// sched_barrier(0) pins subsequent ds_reads below the gate.
#define GATE() do {                                                            \
    const volatile int* vf_ = (const volatile int*)flags;                      \
    int mn_; unsigned sp_ = 0;                                                 \
    do {                                                                       \
      const int a0_ = vf_[0], a1_ = vf_[1], a2_ = vf_[2], a3_ = vf_[3];        \
      const int a4_ = vf_[4], a5_ = vf_[5], a6_ = vf_[6], a7_ = vf_[7];        \
      const int b0_ = a0_ < a1_ ? a0_ : a1_;                                   \
      const int b1_ = a2_ < a3_ ? a2_ : a3_;                                   \
      const int b2_ = a4_ < a5_ ? a4_ : a5_;                                   \
      const int b3_ = a6_ < a7_ ? a6_ : a7_;                                   \
      const int c0_ = b0_ < b1_ ? b0_ : b1_;                                   \
      const int c1_ = b2_ < b3_ ? b2_ : b3_;                                   \
      mn_ = c0_ < c1_ ? c0_ : c1_;                                             \
    } while (mn_ < t && ++sp_ < (1u << 22));                                   \
    __builtin_amdgcn_sched_barrier(0);                                         \
  } while (0)

__global__ __launch_bounds__(512, 2)
void VanillaRNN_70025146794452_kernel(
    const float* __restrict__ Whh,  // [512][512]
    const float* __restrict__ Wph,  // [512][10]
    const float* __restrict__ bp,   // [10]
    const char* __restrict__ U,     // precomputed, swizzled f16
    float* __restrict__ out)        // [256][10]
{
  const int tid  = threadIdx.x;
  const int lane = tid & 63;
  const int w    = tid >> 6;
  const int n16  = lane & 15;
  const int kq   = lane >> 4;
  const int rbase = blockIdx.x * NB;
  const int cwave = w * 64;

  extern __shared__ char smem[];
  char* Ab  = smem;                                  // [3][NB][APITCH]
  char* Wlw = smem + WLDS_OFF + w * WWAVE_BYTES;     // this wave's LDS fp8 wts
  int*  flags = (int*)(smem + FLAGS_OFF);            // flags[v]=tau: h(tau) region v ready

  // -------- preload: f16 weight A-frags (h-k in [0,320)), 40 frags
  short8 wr[KS_F16][NTW];
  #pragma unroll
  for (int s = 0; s < KS_F16; ++s) {
    #pragma unroll
    for (int nt = 0; nt < NTW; ++nt) {
      const int c = cwave + nt * 16 + n16;
      short8 f;
      #pragma unroll
      for (int j = 0; j < 8; ++j)
        f[j] = f16b(Whh[(size_t)(s * 32 + kq * 8 + j) * H_DIM + c]);
      wr[s][nt] = f;
    }
  }
  // -------- preload: reg-resident fp8 weight A-frags (h-k in [320,384))
  long long wf8[KS_REG8][NTW];
  #pragma unroll
  for (int s = 0; s < KS_REG8; ++s) {
    #pragma unroll
    for (int nt = 0; nt < NTW; ++nt) {
      const int c  = cwave + nt * 16 + n16;
      const int k0 = (KS_F16 + s) * 32 + kq * 8;
      unsigned int lo = 0, hi = 0;
      #pragma unroll
      for (int bi = 0; bi < 4; ++bi) {
        lo |= ((unsigned int)f32_to_fp8(Whh[(size_t)(k0 + bi) * H_DIM + c] * WSCALE)) << (8 * bi);
        hi |= ((unsigned int)f32_to_fp8(Whh[(size_t)(k0 + 4 + bi) * H_DIM + c] * WSCALE)) << (8 * bi);
      }
      wf8[s][nt] = (long long)(((unsigned long long)hi << 32) | lo);
    }
  }
  // -------- preload: LDS fp8 weight A-frags (h-k in [384,512))
  for (int sl = 0; sl < KS_LDS8; ++sl) {
    for (int half = 0; half < 2; ++half) {
      const int k0 = (KS_F16 + KS_REG8 + sl) * 32 + kq * 8;
      unsigned int bqq[4];
      #pragma unroll
      for (int hh = 0; hh < 2; ++hh) {
        const int c = cwave + (2 * half + hh) * 16 + n16;
        #pragma unroll
        for (int u = 0; u < 2; ++u) {
          unsigned int acc = 0;
          #pragma unroll
          for (int bi = 0; bi < 4; ++bi)
            acc |= ((unsigned int)f32_to_fp8(Whh[(size_t)(k0 + u * 4 + bi) * H_DIM + c] * WSCALE)) << (8 * bi);
          bqq[hh * 2 + u] = acc;
        }
      }
      uint4v pk; pk.x = bqq[0]; pk.y = bqq[1]; pk.z = bqq[2]; pk.w = bqq[3];
      *(uint4v*)(Wlw + (size_t)(sl * 2 + half) * 1024 + lane * 16) = pk;
    }
  }

  // -------- prologue: zero all 3 A buffers (h_0 = 0), flags, prefetch U(t=0)
  for (int i = tid; i < ABUF3 / 4; i += 512) ((int*)Ab)[i] = 0;
  if (tid < 8) flags[tid] = 0;
  uint4v Upf0, Upf1;
  {
    const char* up = U + (((size_t)0 * NBLK + blockIdx.x) * 512 + tid) * 32;
    Upf0 = *(const uint4v*)up;
    Upf1 = *(const uint4v*)(up + 16);
  }
  __syncthreads();   // the ONLY all-wave barrier before the loop

  f32x4 C[NTW], C2[NTW];

  // -------- main recurrence: no barriers; one gate/step; triple buffer
  for (int t = 0; t < T_SEQ; ++t) {
    char* Ac = Ab + (t % 3) * (NB * APITCH);
    char* An = Ab + ((t + 1) % 3) * (NB * APITCH);

    // C-init from prefetched U
    C[0][0]=f16f(Upf0.x&0xffff); C[0][1]=f16f(Upf0.x>>16);
    C[0][2]=f16f(Upf0.y&0xffff); C[0][3]=f16f(Upf0.y>>16);
    C[1][0]=f16f(Upf0.z&0xffff); C[1][1]=f16f(Upf0.z>>16);
    C[1][2]=f16f(Upf0.w&0xffff); C[1][3]=f16f(Upf0.w>>16);
    C[2][0]=f16f(Upf1.x&0xffff); C[2][1]=f16f(Upf1.x>>16);
    C[2][2]=f16f(Upf1.y&0xffff); C[2][3]=f16f(Upf1.y>>16);
    C[3][0]=f16f(Upf1.z&0xffff); C[3][1]=f16f(Upf1.z>>16);
    C[3][2]=f16f(Upf1.w&0xffff); C[3][3]=f16f(Upf1.w>>16);
    #pragma unroll
    for (int nt = 0; nt < NTW; ++nt) C2[nt] = (f32x4){0.f, 0.f, 0.f, 0.f};

    // prefetch U(t+1)
    {
      const int t1 = (t + 1 < T_SEQ) ? (t + 1) : (T_SEQ - 1);
      const char* up = U + (((size_t)t1 * NBLK + blockIdx.x) * 512 + tid) * 32;
      Upf0 = *(const uint4v*)up;
      Upf1 = *(const uint4v*)(up + 16);
    }

    // ---- own region first (self-produced last step; no wait) ----
    __builtin_amdgcn_s_setprio(1);
    switch (w) {
      case 0: MF16(0); MF16(1); break;
      case 1: MF16(2); MF16(3); break;
      case 2: MF16(4); MF16(5); break;
      case 3: MF16(6); MF16(7); break;
      case 4: MF16(8); MF16(9); break;
      case 5: MR8(0);  MR8(1);  break;
      case 6: ML8(0);  ML8(1);  break;
      default: ML8(2); ML8(3);  break;
    }
    __builtin_amdgcn_s_setprio(0);

    // ---- one gate: wait for all regions of h(t) ----
    GATE();

    // ---- remaining 14 K-steps, fixed order, wave-uniform skips ----
    __builtin_amdgcn_s_setprio(1);
    if (w != 0) { MF16(0); MF16(1); }
    if (w != 1) { MF16(2); MF16(3); }
    if (w != 2) { MF16(4); MF16(5); }
    if (w != 3) { MF16(6); MF16(7); }
    if (w != 4) { MF16(8); MF16(9); }
    if (w != 5) { MR8(0);  MR8(1);  }
    if (w != 6) { ML8(0);  ML8(1);  }
    if (w != 7) { ML8(2);  ML8(3);  }
    __builtin_amdgcn_s_setprio(0);

    // ---- epilogue: fold + tanh + packed store to OWN region of An ----
    char* drow = An + n16 * APITCH;
    if (cwave < HSPLIT) {            // waves 0..4: f16 region
      #pragma unroll
      for (int nt = 0; nt < NTW; ++nt) {
        const int c0 = cwave + nt * 16 + kq * 4;
        float v0 = fast_tanh(fmaf(C2[nt][0], UNSCALE, C[nt][0]));
        float v1 = fast_tanh(fmaf(C2[nt][1], UNSCALE, C[nt][1]));
        float v2 = fast_tanh(fmaf(C2[nt][2], UNSCALE, C[nt][2]));
        float v3 = fast_tanh(fmaf(C2[nt][3], UNSCALE, C[nt][3]));
        uint2v o; o.x = pk2h(v0, v1); o.y = pk2h(v2, v3);
        *(uint2v*)(drow + c0 * 2) = o;
      }
    } else {                          // waves 5..7: fp8 region
      #pragma unroll
      for (int nt = 0; nt < NTW; ++nt) {
        const int c0 = cwave + nt * 16 + kq * 4;
        float v0 = fast_tanh(fmaf(C2[nt][0], UNSCALE, C[nt][0]));
        float v1 = fast_tanh(fmaf(C2[nt][1], UNSCALE, C[nt][1]));
        float v2 = fast_tanh(fmaf(C2[nt][2], UNSCALE, C[nt][2]));
        float v3 = fast_tanh(fmaf(C2[nt][3], UNSCALE, C[nt][3]));
        *(unsigned int*)(drow + FP8OFF + (c0 - HSPLIT)) =
            pk4fp8(v0 * HSCALE, v1 * HSCALE, v2 * HSCALE, v3 * HSCALE);
      }
    }

    // release: region w of h(t+1) ready (orders the ds_writes above)
    if (lane == 0)
      __hip_atomic_store(&flags[w], t + 1, __ATOMIC_RELEASE,
                         __HIP_MEMORY_SCOPE_WORKGROUP);
  }

  __syncthreads();
  // h_T in buffer T_SEQ % 3 == 1. Projection: 16 rows x 10 classes per block.
  if (tid < NB * 10) {
    const int r = tid / 10, c = tid % 10;
    const char* row = Ab + (T_SEQ % 3) * (NB * APITCH) + r * APITCH;
    float acc = bp[c];
    #pragma unroll 8
    for (int k = 0; k < HSPLIT; ++k)
      acc += f16f(*(const unsigned short*)(row + k * 2)) * Wph[k * 10 + c];
    #pragma unroll 8
    for (int k = HSPLIT; k < H_DIM; ++k)
      acc += fp8_to_f32((unsigned char)row[FP8OFF + (k - HSPLIT)]) * (1.f / HSCALE) * Wph[k * 10 + c];
    out[(size_t)(rbase + r) * 10 + c] = acc;
  }
}

// ============================ fallback (R2 verbatim, 2833us) =================
#define FB_APITCH  1040
#define FB_FP8OFF  768
#define FB_ABUF    (2 * NB * FB_APITCH)
#define FB_WWAVE   (6 * 2 * 1024)
#define FB_SMEM    (FB_ABUF + 8 * FB_WWAVE)       // 131584

__global__ __launch_bounds__(512, 2)
void rnn_fallback_kernel(
    const float* __restrict__ x, const float* __restrict__ Whx,
    const float* __restrict__ Whh, const float* __restrict__ Wph,
    const float* __restrict__ bh, const float* __restrict__ bp,
    float* __restrict__ out)
{
  const int tid = threadIdx.x, lane = tid & 63, w = tid >> 6;
  const int n16 = lane & 15, kq = lane >> 4;
  const int rbase = blockIdx.x * NB, cwave = w * 64;
  extern __shared__ char smem[];
  char* Ab  = smem;
  char* Wlw = smem + FB_ABUF + w * FB_WWAVE;

  short8 wr[12 * 4];
  #pragma unroll
  for (int s = 0; s < 12; ++s)
    #pragma unroll
    for (int nt = 0; nt < 4; ++nt) {
      const int c = cwave + nt * 16 + n16, k0 = s * 32 + kq * 8;
      short8 f;
      #pragma unroll
      for (int j = 0; j < 8; ++j) {
        const int k = k0 + j;
        const float* src = (k < D_IN) ? (Whx + (size_t)k * H_DIM + c)
                                      : (Whh + (size_t)(k - D_IN) * H_DIM + c);
        f[j] = bf16b(*src);
      }
      wr[s * 4 + nt] = f;
    }
  for (int s = 0; s < 6; ++s)
    for (int pp = 0; pp < 2; ++pp) {
      const int k0 = (12 + s) * 32 + kq * 8;
      unsigned int bq[4];
      #pragma unroll
      for (int half = 0; half < 2; ++half) {
        const int c = cwave + (2 * pp + half) * 16 + n16;
        #pragma unroll
        for (int u = 0; u < 2; ++u) {
          unsigned int acc = 0;
          #pragma unroll
          for (int bi = 0; bi < 4; ++bi)
            acc |= ((unsigned int)f32_to_fp8(Whh[(size_t)(k0 + u * 4 + bi - D_IN) * H_DIM + c] * WSCALE)) << (8 * bi);
          bq[half * 2 + u] = acc;
        }
      }
      uint4v pk; pk.x = bq[0]; pk.y = bq[1]; pk.z = bq[2]; pk.w = bq[3];
      *(uint4v*)(Wlw + (size_t)(s * 2 + pp) * 1024 + lane * 16) = pk;
    }
  float bhreg[4];
  #pragma unroll
  for (int nt = 0; nt < 4; ++nt) bhreg[nt] = bh[cwave + nt * 16 + n16];
  for (int i = tid; i < FB_ABUF / 4; i += 512) ((int*)Ab)[i] = 0;
  const int xr = (tid >> 4) & 15, xc4 = (tid & 15) * 4;
  if (tid < 256) {
    const f32x4 xv = *(const f32x4*)(x + ((size_t)(rbase + xr) * T_SEQ) * D_IN + xc4);
    short4v s4; s4[0]=bf16b(xv.x); s4[1]=bf16b(xv.y); s4[2]=bf16b(xv.z); s4[3]=bf16b(xv.w);
    *(short4v*)(Ab + xr * FB_APITCH + xc4 * 2) = s4;
  }
  f32x4 C[4], C2[4];
  for (int t = 0; t < T_SEQ; ++t) {
    __syncthreads();
    char* Ac = Ab + (t & 1) * (NB * FB_APITCH);
    char* An = Ab + ((t + 1) & 1) * (NB * FB_APITCH);
    const int t1 = (t + 1 < T_SEQ) ? (t + 1) : (T_SEQ - 1);
    f32x4 xv;
    if (tid < 256)
      xv = *(const f32x4*)(x + ((size_t)(rbase + xr) * T_SEQ + t1) * D_IN + xc4);
    #pragma unroll
    for (int nt = 0; nt < 4; ++nt) {
      C[nt] = (f32x4){0.f,0.f,0.f,0.f}; C2[nt] = (f32x4){0.f,0.f,0.f,0.f};
    }
    #pragma unroll
    for (int s = 0; s < 12; ++s) {
      const short8 a = *(const short8*)(Ac + n16 * FB_APITCH + s * 64 + kq * 16);
      #pragma unroll
      for (int nt = 0; nt < 4; ++nt)
        C[nt] = __builtin_amdgcn_mfma_f32_16x16x32_bf16(a, wr[s * 4 + nt], C[nt], 0, 0, 0);
    }
    #pragma unroll
    for (int s = 0; s < 6; ++s) {
      const long long a8 = *(const long long*)(Ac + n16 * FB_APITCH + FB_FP8OFF + s * 32 + kq * 8);
      #pragma unroll
      for (int pp = 0; pp < 2; ++pp) {
        const uint4v q = *(const uint4v*)(Wlw + (size_t)(s * 2 + pp) * 1024 + lane * 16);
        const long long b0 = (long long)(((unsigned long long)q.y << 32) | q.x);
        const long long b1 = (long long)(((unsigned long long)q.w << 32) | q.z);
        C2[2*pp]   = __builtin_amdgcn_mfma_f32_16x16x32_fp8_fp8(a8, b0, C2[2*pp],   0, 0, 0);
        C2[2*pp+1] = __builtin_amdgcn_mfma_f32_16x16x32_fp8_fp8(a8, b1, C2[2*pp+1], 0, 0, 0);
      }
    }
    if (tid < 256) {
      short4v s4; s4[0]=bf16b(xv.x); s4[1]=bf16b(xv.y); s4[2]=bf16b(xv.z); s4[3]=bf16b(xv.w);
      *(short4v*)(An + xr * FB_APITCH + xc4 * 2) = s4;
    }
    const int row0 = kq * 4;
    #pragma unroll
    for (int nt = 0; nt < 4; ++nt) {
      const int cbase = cwave + nt * 16;
      #pragma unroll
      for (int i = 0; i < 4; ++i) {
        const float v = fast_tanh(fmaf(C2[nt][i], UNSCALE, C[nt][i]) + bhreg[nt]);
        char* dst = An + (row0 + i) * FB_APITCH;
        if (cbase < 320) *(short*)(dst + 128 + (cbase + n16) * 2) = bf16b(v);
        else dst[FB_FP8OFF + (cbase + n16 - 320)] = f32_to_fp8(v * HSCALE);
      }
    }
  }
  __syncthreads();
  if (tid < NB * 10) {
    const int r = tid / 10, c = tid % 10;
    const char* row = Ab + r * FB_APITCH;
    float acc = bp[c];
    #pragma unroll 8
    for (int k = 0; k < 320; ++k) {
      const __hip_bfloat16 hb = __builtin_bit_cast(__hip_bfloat16, *(const short*)(row + 128 + k * 2));
      acc += __bfloat162float(hb) * Wph[k * 10 + c];
    }
    #pragma unroll 8
    for (int k = 320; k < H_DIM; ++k)
      acc += fp8_to_f32((unsigned char)row[FB_FP8OFF + (k - 320)]) * (1.f / HSCALE) * Wph[k * 10 + c];
    out[(size_t)(rbase + r) * 10 + c] = acc;
  }
}

extern "C" void kernel_launch(void* const* d_in, const int* in_sizes, int n_in,
                              void* d_out, int out_size, void* d_ws, size_t ws_size,
                              hipStream_t stream) {
  const float* x   = (const float*)d_in[0];
  const float* Whx = (const float*)d_in[1];
  const float* Whh = (const float*)d_in[2];
  const float* Wph = (const float*)d_in[3];
  const float* bh  = (const float*)d_in[4];
  const float* bp  = (const float*)d_in[5];
  float* out = (float*)d_out;

  if (ws_size >= U_BYTES) {
    char* U = (char*)d_ws;
    (void)hipFuncSetAttribute((const void*)VanillaRNN_70025146794452_kernel,
                              hipFuncAttributeMaxDynamicSharedMemorySize, SMEM_TOTAL);
    rnn_u_precompute<<<dim3(NBLK, T_SEQ / TTP), dim3(512), 0, stream>>>(x, Whx, bh, U);
    VanillaRNN_70025146794452_kernel<<<dim3(NBLK), dim3(512), SMEM_TOTAL, stream>>>(
        Whh, Wph, bp, U, out);
  } else {
    (void)hipFuncSetAttribute((const void*)rnn_fallback_kernel,
                              hipFuncAttributeMaxDynamicSharedMemorySize, FB_SMEM);
    rnn_fallback_kernel<<<dim3(NBLK), dim3(512), FB_SMEM, stream>>>(
        x, Whx, Whh, Wph, bh, bp, out);
  }
}

// Round 4
// 1847.840 us; speedup vs baseline: 1.2840x; 1.2840x over previous
//
#include <hip/hip_runtime.h>
#include <hip/hip_bf16.h>
#include <hip/hip_fp8.h>
#include <cstdint>
#include <cstddef>

// VanillaRNN: h_{t+1} = tanh(x_t @ Whx + h_t @ Whh + bh), p = h_T @ Wph + bp
// B=256, T=1024, D=64, H=512, C=10.
//
// R12 = R8 (best measured: 1713us consumer / 1887us total) + cheaper tanh.
// Session lessons (R9/R10/R11 all regressed; do not retry):
//  - R9: cross-CU per-step exchange through L3/agent fences = +3us/step. Dead.
//  - R10/R11: intra-block flag gating (per-region acquire OR single-gate with
//    wave-uniform skip branches) puts control flow inside the K-loop; hipcc
//    then drains lgkmcnt at every BB boundary and the ds_read->MFMA pipeline
//    collapses (MfmaUtil 51%->44%/40% on-CU). The straight-line K-loop with
//    ONE __syncthreads per step is the best schedulable shape at HIP level.
//  - R12 change: fast_tanh via 1 - 2/(exp2(2x*log2e)+1): 5 VALU ops vs 8,
//    clamp-free (inf/0 saturate to +-1 exactly); saves ~48 VALU inst/thread
//    per step in the serial epilogue phase.
// Fallback (ws < 256MiB): R2 kernel verbatim.

#define T_SEQ   1024
#define D_IN    64
#define H_DIM   512
#define NB      16
#define NBLK    16
#define NTW     4            // N-tiles (16 cols) per wave; wave owns 64 cols
#define KS_F16  10           // f16 K-steps: h[0,320)  (R3 split)
#define KS_REG8 2            // fp8 K-steps with reg weights: h[320,384)
#define KS_LDS8 4            // fp8 K-steps with LDS weights: h[384,512)
#define HSPLIT  320          // h cols >= HSPLIT stored fp8
#define APITCH  848          // bytes per A row: 640 f16 + 192 fp8 + 16 pad
#define FP8OFF  640
#define ABUF_BYTES (2 * NB * APITCH)              // 27136
#define WWAVE_BYTES (KS_LDS8 * 2 * 1024)          // 8192
#define WLDS_BYTES (8 * WWAVE_BYTES)              // 65536
#define SMEM_TOTAL (ABUF_BYTES + WLDS_BYTES)      // 92672
#define WSCALE  256.0f
#define HSCALE  128.0f
#define UNSCALE (1.0f / 32768.0f)
#define U_BYTES ((size_t)T_SEQ * NBLK * 512 * 32) // 268435456 (f16 U, all t)
#define TTP     64           // t-steps per precompute block (grid 16x16)

typedef __attribute__((ext_vector_type(8))) short  short8;
typedef __attribute__((ext_vector_type(4))) short  short4v;
typedef __attribute__((ext_vector_type(4))) float  f32x4;
typedef __attribute__((ext_vector_type(4))) unsigned int uint4v;
typedef __attribute__((ext_vector_type(2))) unsigned int uint2v;

static __device__ __forceinline__ short f16b(float v) {
  return __builtin_bit_cast(short, (_Float16)v);
}
static __device__ __forceinline__ short bf16b(float v) {
  return __builtin_bit_cast(short, __float2bfloat16(v));
}
static __device__ __forceinline__ float f16f(unsigned short u) {
  return (float)__builtin_bit_cast(_Float16, (short)u);
}
static __device__ __forceinline__ unsigned int pk2h(float a, float b) {
#if defined(__has_builtin) && __has_builtin(__builtin_amdgcn_cvt_pkrtz)
  return __builtin_bit_cast(unsigned int, __builtin_amdgcn_cvt_pkrtz(a, b));
#else
  return (unsigned int)(unsigned short)f16b(a) |
         ((unsigned int)(unsigned short)f16b(b) << 16);
#endif
}
// tanh(x) = 1 - 2/(e^{2x}+1); exp2 overflow/underflow saturate to +-1 exactly,
// so no clamp is needed. 5 VALU ops (mul, exp2, add, rcp, fma).
static __device__ __forceinline__ float fast_tanh(float x) {
  const float t = __builtin_amdgcn_exp2f(x * 2.885390081777927f); // 2*log2(e)
  return 1.f - 2.f * __builtin_amdgcn_rcpf(t + 1.f);
}
static __device__ __forceinline__ unsigned char f32_to_fp8(float v) {
#if defined(__has_builtin) && __has_builtin(__builtin_amdgcn_cvt_pk_fp8_f32)
  const int r = __builtin_amdgcn_cvt_pk_fp8_f32(v, v, 0, false);
  return (unsigned char)(r & 0xff);
#else
  __hip_fp8_e4m3 f(v);
  return (unsigned char)f.__x;
#endif
}
static __device__ __forceinline__ unsigned int pk4fp8(float a, float b, float c, float d) {
#if defined(__has_builtin) && __has_builtin(__builtin_amdgcn_cvt_pk_fp8_f32)
  int r = __builtin_amdgcn_cvt_pk_fp8_f32(a, b, 0, false);
  r = __builtin_amdgcn_cvt_pk_fp8_f32(c, d, r, true);
  return (unsigned int)r;
#else
  return (unsigned int)f32_to_fp8(a) | ((unsigned int)f32_to_fp8(b) << 8) |
         ((unsigned int)f32_to_fp8(c) << 16) | ((unsigned int)f32_to_fp8(d) << 24);
#endif
}
static __device__ __forceinline__ float fp8_to_f32(unsigned char b) {
  __hip_fp8_e4m3 f;
  f.__x = (__hip_fp8_storage_t)b;
  return (float)f;
}

// ============================ precompute: U = x@Whx + bh =====================
// U slot: thread (wg, tid) at step t owns 32 B at ((t*NBLK+wg)*512+tid)*32.
// Grid (NBLK, 16): block = (wg, 64-step chunk); 256 blocks = 1/CU. Weights
// preloaded once; x(t+1) prefetched so the loop runs at store-BW.
__global__ __launch_bounds__(512, 2)
void rnn_u_precompute(const float* __restrict__ x, const float* __restrict__ Whx,
                      const float* __restrict__ bh, char* __restrict__ U)
{
  const int tid  = threadIdx.x;
  const int lane = tid & 63;
  const int w    = tid >> 6;
  const int n16  = lane & 15;
  const int kq   = lane >> 4;
  const int wg   = blockIdx.x;
  const int cwave = w * 64;

  // A-operand frags: Whx^T. lane m=n16 -> col c; holds Whx[k0+kq*8+j][c].
  short8 wa[2][NTW];
  #pragma unroll
  for (int s = 0; s < 2; ++s) {
    #pragma unroll
    for (int nt = 0; nt < NTW; ++nt) {
      const int c = cwave + nt * 16 + n16;
      short8 f;
      #pragma unroll
      for (int j = 0; j < 8; ++j)
        f[j] = f16b(Whx[(size_t)(s * 32 + kq * 8 + j) * H_DIM + c]);
      wa[s][nt] = f;
    }
  }
  f32x4 bb[NTW];
  #pragma unroll
  for (int nt = 0; nt < NTW; ++nt) {
    #pragma unroll
    for (int i = 0; i < 4; ++i) bb[nt][i] = bh[cwave + nt * 16 + kq * 4 + i];
  }

  const int b = wg * NB + n16;
  const float* pxb = x + (size_t)b * T_SEQ * D_IN + kq * 8;
  const int t0 = blockIdx.y * TTP;

  // x regs for current step (double-buffered against next)
  f32x4 c0, c1, c2, c3;
  {
    const float* p = pxb + (size_t)t0 * D_IN;
    c0 = *(const f32x4*)p;        c1 = *(const f32x4*)(p + 4);
    c2 = *(const f32x4*)(p + 32); c3 = *(const f32x4*)(p + 36);
  }

  for (int tt = 0; tt < TTP; ++tt) {
    const int t = t0 + tt;
    f32x4 n0, n1, n2, n3;
    if (tt + 1 < TTP) {
      const float* p = pxb + (size_t)(t + 1) * D_IN;
      n0 = *(const f32x4*)p;        n1 = *(const f32x4*)(p + 4);
      n2 = *(const f32x4*)(p + 32); n3 = *(const f32x4*)(p + 36);
    }
    short8 xb0, xb1;
    xb0[0]=f16b(c0.x); xb0[1]=f16b(c0.y); xb0[2]=f16b(c0.z); xb0[3]=f16b(c0.w);
    xb0[4]=f16b(c1.x); xb0[5]=f16b(c1.y); xb0[6]=f16b(c1.z); xb0[7]=f16b(c1.w);
    xb1[0]=f16b(c2.x); xb1[1]=f16b(c2.y); xb1[2]=f16b(c2.z); xb1[3]=f16b(c2.w);
    xb1[4]=f16b(c3.x); xb1[5]=f16b(c3.y); xb1[6]=f16b(c3.z); xb1[7]=f16b(c3.w);

    f32x4 D[NTW];
    #pragma unroll
    for (int nt = 0; nt < NTW; ++nt) {
      D[nt] = bb[nt];
      D[nt] = __builtin_amdgcn_mfma_f32_16x16x32_f16(wa[0][nt], xb0, D[nt], 0, 0, 0);
      D[nt] = __builtin_amdgcn_mfma_f32_16x16x32_f16(wa[1][nt], xb1, D[nt], 0, 0, 0);
    }
    uint4v o0, o1;
    o0.x = pk2h(D[0][0], D[0][1]); o0.y = pk2h(D[0][2], D[0][3]);
    o0.z = pk2h(D[1][0], D[1][1]); o0.w = pk2h(D[1][2], D[1][3]);
    o1.x = pk2h(D[2][0], D[2][1]); o1.y = pk2h(D[2][2], D[2][3]);
    o1.z = pk2h(D[3][0], D[3][1]); o1.w = pk2h(D[3][2], D[3][3]);
    char* dst = U + (((size_t)t * NBLK + wg) * 512 + tid) * 32;
    *(uint4v*)dst = o0;
    *(uint4v*)(dst + 16) = o1;

    c0 = n0; c1 = n1; c2 = n2; c3 = n3;
  }
}

// ============================ main recurrence (R8 structure) =================
__global__ __launch_bounds__(512, 2)
void VanillaRNN_70025146794452_kernel(
    const float* __restrict__ Whh,  // [512][512]
    const float* __restrict__ Wph,  // [512][10]
    const float* __restrict__ bp,   // [10]
    const char* __restrict__ U,     // precomputed, swizzled f16
    float* __restrict__ out)        // [256][10]
{
  const int tid  = threadIdx.x;
  const int lane = tid & 63;
  const int w    = tid >> 6;
  const int n16  = lane & 15;
  const int kq   = lane >> 4;
  const int rbase = blockIdx.x * NB;
  const int cwave = w * 64;

  extern __shared__ char smem[];
  char* Ab  = smem;                                  // [2][NB][APITCH]
  char* Wlw = smem + ABUF_BYTES + w * WWAVE_BYTES;   // this wave's LDS fp8 wts

  // -------- preload: f16 weight A-frags (h-k in [0,320)), 40 frags
  short8 wr[KS_F16][NTW];
  #pragma unroll
  for (int s = 0; s < KS_F16; ++s) {
    #pragma unroll
    for (int nt = 0; nt < NTW; ++nt) {
      const int c = cwave + nt * 16 + n16;
      short8 f;
      #pragma unroll
      for (int j = 0; j < 8; ++j)
        f[j] = f16b(Whh[(size_t)(s * 32 + kq * 8 + j) * H_DIM + c]);
      wr[s][nt] = f;
    }
  }
  // -------- preload: reg-resident fp8 weight A-frags (h-k in [320,384))
  long long wf8[KS_REG8][NTW];
  #pragma unroll
  for (int s = 0; s < KS_REG8; ++s) {
    #pragma unroll
    for (int nt = 0; nt < NTW; ++nt) {
      const int c  = cwave + nt * 16 + n16;
      const int k0 = (KS_F16 + s) * 32 + kq * 8;
      unsigned int lo = 0, hi = 0;
      #pragma unroll
      for (int bi = 0; bi < 4; ++bi) {
        lo |= ((unsigned int)f32_to_fp8(Whh[(size_t)(k0 + bi) * H_DIM + c] * WSCALE)) << (8 * bi);
        hi |= ((unsigned int)f32_to_fp8(Whh[(size_t)(k0 + 4 + bi) * H_DIM + c] * WSCALE)) << (8 * bi);
      }
      wf8[s][nt] = (long long)(((unsigned long long)hi << 32) | lo);
    }
  }
  // -------- preload: LDS fp8 weight A-frags (h-k in [384,512))
  for (int sl = 0; sl < KS_LDS8; ++sl) {
    for (int half = 0; half < 2; ++half) {
      const int k0 = (KS_F16 + KS_REG8 + sl) * 32 + kq * 8;
      unsigned int bqq[4];
      #pragma unroll
      for (int hh = 0; hh < 2; ++hh) {
        const int c = cwave + (2 * half + hh) * 16 + n16;
        #pragma unroll
        for (int u = 0; u < 2; ++u) {
          unsigned int acc = 0;
          #pragma unroll
          for (int bi = 0; bi < 4; ++bi)
            acc |= ((unsigned int)f32_to_fp8(Whh[(size_t)(k0 + u * 4 + bi) * H_DIM + c] * WSCALE)) << (8 * bi);
          bqq[hh * 2 + u] = acc;
        }
      }
      uint4v pk; pk.x = bqq[0]; pk.y = bqq[1]; pk.z = bqq[2]; pk.w = bqq[3];
      *(uint4v*)(Wlw + (size_t)(sl * 2 + half) * 1024 + lane * 16) = pk;
    }
  }

  // -------- prologue: zero both A buffers (h_0 = 0), prefetch U(t=0)
  for (int i = tid; i < ABUF_BYTES / 4; i += 512) ((int*)Ab)[i] = 0;
  uint4v Upf0, Upf1;
  {
    const char* up = U + (((size_t)0 * NBLK + blockIdx.x) * 512 + tid) * 32;
    Upf0 = *(const uint4v*)up;
    Upf1 = *(const uint4v*)(up + 16);
  }

  f32x4 C[NTW], C2[NTW];

  // -------- main recurrence (C || C2 chains, fold at epilogue)
  for (int t = 0; t < T_SEQ; ++t) {
    __syncthreads();
    char* Ac = Ab + (t & 1) * (NB * APITCH);
    char* An = Ab + ((t + 1) & 1) * (NB * APITCH);

    short8 hb = *(const short8*)(Ac + n16 * APITCH + 0 * 64 + kq * 16);

    // C-init from prefetched U
    C[0][0]=f16f(Upf0.x&0xffff); C[0][1]=f16f(Upf0.x>>16);
    C[0][2]=f16f(Upf0.y&0xffff); C[0][3]=f16f(Upf0.y>>16);
    C[1][0]=f16f(Upf0.z&0xffff); C[1][1]=f16f(Upf0.z>>16);
    C[1][2]=f16f(Upf0.w&0xffff); C[1][3]=f16f(Upf0.w>>16);
    C[2][0]=f16f(Upf1.x&0xffff); C[2][1]=f16f(Upf1.x>>16);
    C[2][2]=f16f(Upf1.y&0xffff); C[2][3]=f16f(Upf1.y>>16);
    C[3][0]=f16f(Upf1.z&0xffff); C[3][1]=f16f(Upf1.z>>16);
    C[3][2]=f16f(Upf1.w&0xffff); C[3][3]=f16f(Upf1.w>>16);
    #pragma unroll
    for (int nt = 0; nt < NTW; ++nt) C2[nt] = (f32x4){0.f, 0.f, 0.f, 0.f};

    // prefetch U(t+1)
    {
      const int t1 = (t + 1 < T_SEQ) ? (t + 1) : (T_SEQ - 1);
      const char* up = U + (((size_t)t1 * NBLK + blockIdx.x) * 512 + tid) * 32;
      Upf0 = *(const uint4v*)up;
      Upf1 = *(const uint4v*)(up + 16);
    }

    // f16 phase (C-chain)
    #pragma unroll
    for (int s = 0; s < KS_F16; ++s) {
      const short8 a = hb;
      if (s + 1 < KS_F16)
        hb = *(const short8*)(Ac + n16 * APITCH + (s + 1) * 64 + kq * 16);
      #pragma unroll
      for (int nt = 0; nt < NTW; ++nt)
        C[nt] = __builtin_amdgcn_mfma_f32_16x16x32_f16(wr[s][nt], a, C[nt], 0, 0, 0);
    }
    // fp8 phase (independent C2-chain)
    #pragma unroll
    for (int s = 0; s < KS_REG8; ++s) {
      const long long h8 = *(const long long*)(Ac + n16 * APITCH + FP8OFF + s * 32 + kq * 8);
      #pragma unroll
      for (int nt = 0; nt < NTW; ++nt)
        C2[nt] = __builtin_amdgcn_mfma_f32_16x16x32_fp8_fp8(wf8[s][nt], h8, C2[nt], 0, 0, 0);
    }
    #pragma unroll
    for (int sl = 0; sl < KS_LDS8; ++sl) {
      const long long h8 = *(const long long*)(Ac + n16 * APITCH + FP8OFF + (KS_REG8 + sl) * 32 + kq * 8);
      const uint4v q0 = *(const uint4v*)(Wlw + (size_t)(sl * 2 + 0) * 1024 + lane * 16);
      const uint4v q1 = *(const uint4v*)(Wlw + (size_t)(sl * 2 + 1) * 1024 + lane * 16);
      const long long w0 = (long long)(((unsigned long long)q0.y << 32) | q0.x);
      const long long w1 = (long long)(((unsigned long long)q0.w << 32) | q0.z);
      const long long w2 = (long long)(((unsigned long long)q1.y << 32) | q1.x);
      const long long w3 = (long long)(((unsigned long long)q1.w << 32) | q1.z);
      C2[0] = __builtin_amdgcn_mfma_f32_16x16x32_fp8_fp8(w0, h8, C2[0], 0, 0, 0);
      C2[1] = __builtin_amdgcn_mfma_f32_16x16x32_fp8_fp8(w1, h8, C2[1], 0, 0, 0);
      C2[2] = __builtin_amdgcn_mfma_f32_16x16x32_fp8_fp8(w2, h8, C2[2], 0, 0, 0);
      C2[3] = __builtin_amdgcn_mfma_f32_16x16x32_fp8_fp8(w3, h8, C2[3], 0, 0, 0);
    }

    // epilogue: fold + tanh + packed store (D transposed: row n16 = batch,
    // reg i = col kq*4+i)
    char* drow = An + n16 * APITCH;
    if (cwave < HSPLIT) {            // waves 0..4: f16 region
      #pragma unroll
      for (int nt = 0; nt < NTW; ++nt) {
        const int c0 = cwave + nt * 16 + kq * 4;
        float v0 = fast_tanh(fmaf(C2[nt][0], UNSCALE, C[nt][0]));
        float v1 = fast_tanh(fmaf(C2[nt][1], UNSCALE, C[nt][1]));
        float v2 = fast_tanh(fmaf(C2[nt][2], UNSCALE, C[nt][2]));
        float v3 = fast_tanh(fmaf(C2[nt][3], UNSCALE, C[nt][3]));
        uint2v o; o.x = pk2h(v0, v1); o.y = pk2h(v2, v3);
        *(uint2v*)(drow + c0 * 2) = o;
      }
    } else {                          // waves 5..7: fp8 region
      #pragma unroll
      for (int nt = 0; nt < NTW; ++nt) {
        const int c0 = cwave + nt * 16 + kq * 4;
        float v0 = fast_tanh(fmaf(C2[nt][0], UNSCALE, C[nt][0]));
        float v1 = fast_tanh(fmaf(C2[nt][1], UNSCALE, C[nt][1]));
        float v2 = fast_tanh(fmaf(C2[nt][2], UNSCALE, C[nt][2]));
        float v3 = fast_tanh(fmaf(C2[nt][3], UNSCALE, C[nt][3]));
        *(unsigned int*)(drow + FP8OFF + (c0 - HSPLIT)) =
            pk4fp8(v0 * HSCALE, v1 * HSCALE, v2 * HSCALE, v3 * HSCALE);
      }
    }
  }

  __syncthreads();
  // h_T in buffer 0 (T even). Projection: 16 rows x 10 classes per block.
  if (tid < NB * 10) {
    const int r = tid / 10, c = tid % 10;
    const char* row = Ab + r * APITCH;
    float acc = bp[c];
    #pragma unroll 8
    for (int k = 0; k < HSPLIT; ++k)
      acc += f16f(*(const unsigned short*)(row + k * 2)) * Wph[k * 10 + c];
    #pragma unroll 8
    for (int k = HSPLIT; k < H_DIM; ++k)
      acc += fp8_to_f32((unsigned char)row[FP8OFF + (k - HSPLIT)]) * (1.f / HSCALE) * Wph[k * 10 + c];
    out[(size_t)(rbase + r) * 10 + c] = acc;
  }
}

// ============================ fallback (R2 verbatim, 2833us) =================
#define FB_APITCH  1040
#define FB_FP8OFF  768
#define FB_ABUF    (2 * NB * FB_APITCH)
#define FB_WWAVE   (6 * 2 * 1024)
#define FB_SMEM    (FB_ABUF + 8 * FB_WWAVE)       // 131584

__global__ __launch_bounds__(512, 2)
void rnn_fallback_kernel(
    const float* __restrict__ x, const float* __restrict__ Whx,
    const float* __restrict__ Whh, const float* __restrict__ Wph,
    const float* __restrict__ bh, const float* __restrict__ bp,
    float* __restrict__ out)
{
  const int tid = threadIdx.x, lane = tid & 63, w = tid >> 6;
  const int n16 = lane & 15, kq = lane >> 4;
  const int rbase = blockIdx.x * NB, cwave = w * 64;
  extern __shared__ char smem[];
  char* Ab  = smem;
  char* Wlw = smem + FB_ABUF + w * FB_WWAVE;

  short8 wr[12 * 4];
  #pragma unroll
  for (int s = 0; s < 12; ++s)
    #pragma unroll
    for (int nt = 0; nt < 4; ++nt) {
      const int c = cwave + nt * 16 + n16, k0 = s * 32 + kq * 8;
      short8 f;
      #pragma unroll
      for (int j = 0; j < 8; ++j) {
        const int k = k0 + j;
        const float* src = (k < D_IN) ? (Whx + (size_t)k * H_DIM + c)
                                      : (Whh + (size_t)(k - D_IN) * H_DIM + c);
        f[j] = bf16b(*src);
      }
      wr[s * 4 + nt] = f;
    }
  for (int s = 0; s < 6; ++s)
    for (int pp = 0; pp < 2; ++pp) {
      const int k0 = (12 + s) * 32 + kq * 8;
      unsigned int bq[4];
      #pragma unroll
      for (int half = 0; half < 2; ++half) {
        const int c = cwave + (2 * pp + half) * 16 + n16;
        #pragma unroll
        for (int u = 0; u < 2; ++u) {
          unsigned int acc = 0;
          #pragma unroll
          for (int bi = 0; bi < 4; ++bi)
            acc |= ((unsigned int)f32_to_fp8(Whh[(size_t)(k0 + u * 4 + bi - D_IN) * H_DIM + c] * WSCALE)) << (8 * bi);
          bq[half * 2 + u] = acc;
        }
      }
      uint4v pk; pk.x = bq[0]; pk.y = bq[1]; pk.z = bq[2]; pk.w = bq[3];
      *(uint4v*)(Wlw + (size_t)(s * 2 + pp) * 1024 + lane * 16) = pk;
    }
  float bhreg[4];
  #pragma unroll
  for (int nt = 0; nt < 4; ++nt) bhreg[nt] = bh[cwave + nt * 16 + n16];
  for (int i = tid; i < FB_ABUF / 4; i += 512) ((int*)Ab)[i] = 0;
  const int xr = (tid >> 4) & 15, xc4 = (tid & 15) * 4;
  if (tid < 256) {
    const f32x4 xv = *(const f32x4*)(x + ((size_t)(rbase + xr) * T_SEQ) * D_IN + xc4);
    short4v s4; s4[0]=bf16b(xv.x); s4[1]=bf16b(xv.y); s4[2]=bf16b(xv.z); s4[3]=bf16b(xv.w);
    *(short4v*)(Ab + xr * FB_APITCH + xc4 * 2) = s4;
  }
  f32x4 C[4], C2[4];
  for (int t = 0; t < T_SEQ; ++t) {
    __syncthreads();
    char* Ac = Ab + (t & 1) * (NB * FB_APITCH);
    char* An = Ab + ((t + 1) & 1) * (NB * FB_APITCH);
    const int t1 = (t + 1 < T_SEQ) ? (t + 1) : (T_SEQ - 1);
    f32x4 xv;
    if (tid < 256)
      xv = *(const f32x4*)(x + ((size_t)(rbase + xr) * T_SEQ + t1) * D_IN + xc4);
    #pragma unroll
    for (int nt = 0; nt < 4; ++nt) {
      C[nt] = (f32x4){0.f,0.f,0.f,0.f}; C2[nt] = (f32x4){0.f,0.f,0.f,0.f};
    }
    #pragma unroll
    for (int s = 0; s < 12; ++s) {
      const short8 a = *(const short8*)(Ac + n16 * FB_APITCH + s * 64 + kq * 16);
      #pragma unroll
      for (int nt = 0; nt < 4; ++nt)
        C[nt] = __builtin_amdgcn_mfma_f32_16x16x32_bf16(a, wr[s * 4 + nt], C[nt], 0, 0, 0);
    }
    #pragma unroll
    for (int s = 0; s < 6; ++s) {
      const long long a8 = *(const long long*)(Ac + n16 * FB_APITCH + FB_FP8OFF + s * 32 + kq * 8);
      #pragma unroll
      for (int pp = 0; pp < 2; ++pp) {
        const uint4v q = *(const uint4v*)(Wlw + (size_t)(s * 2 + pp) * 1024 + lane * 16);
        const long long b0 = (long long)(((unsigned long long)q.y << 32) | q.x);
        const long long b1 = (long long)(((unsigned long long)q.w << 32) | q.z);
        C2[2*pp]   = __builtin_amdgcn_mfma_f32_16x16x32_fp8_fp8(a8, b0, C2[2*pp],   0, 0, 0);
        C2[2*pp+1] = __builtin_amdgcn_mfma_f32_16x16x32_fp8_fp8(a8, b1, C2[2*pp+1], 0, 0, 0);
      }
    }
    if (tid < 256) {
      short4v s4; s4[0]=bf16b(xv.x); s4[1]=bf16b(xv.y); s4[2]=bf16b(xv.z); s4[3]=bf16b(xv.w);
      *(short4v*)(An + xr * FB_APITCH + xc4 * 2) = s4;
    }
    const int row0 = kq * 4;
    #pragma unroll
    for (int nt = 0; nt < 4; ++nt) {
      const int cbase = cwave + nt * 16;
      #pragma unroll
      for (int i = 0; i < 4; ++i) {
        const float v = fast_tanh(fmaf(C2[nt][i], UNSCALE, C[nt][i]) + bhreg[nt]);
        char* dst = An + (row0 + i) * FB_APITCH;
        if (cbase < 320) *(short*)(dst + 128 + (cbase + n16) * 2) = bf16b(v);
        else dst[FB_FP8OFF + (cbase + n16 - 320)] = f32_to_fp8(v * HSCALE);
      }
    }
  }
  __syncthreads();
  if (tid < NB * 10) {
    const int r = tid / 10, c = tid % 10;
    const char* row = Ab + r * FB_APITCH;
    float acc = bp[c];
    #pragma unroll 8
    for (int k = 0; k < 320; ++k) {
      const __hip_bfloat16 hb = __builtin_bit_cast(__hip_bfloat16, *(const short*)(row + 128 + k * 2));
      acc += __bfloat162float(hb) * Wph[k * 10 + c];
    }
    #pragma unroll 8
    for (int k = 320; k < H_DIM; ++k)
      acc += fp8_to_f32((unsigned char)row[FB_FP8OFF + (k - 320)]) * (1.f / HSCALE) * Wph[k * 10 + c];
    out[(size_t)(rbase + r) * 10 + c] = acc;
  }
}

extern "C" void kernel_launch(void* const* d_in, const int* in_sizes, int n_in,
                              void* d_out, int out_size, void* d_ws, size_t ws_size,
                              hipStream_t stream) {
  const float* x   = (const float*)d_in[0];
  const float* Whx = (const float*)d_in[1];
  const float* Whh = (const float*)d_in[2];
  const float* Wph = (const float*)d_in[3];
  const float* bh  = (const float*)d_in[4];
  const float* bp  = (const float*)d_in[5];
  float* out = (float*)d_out;

  if (ws_size >= U_BYTES) {
    char* U = (char*)d_ws;
    (void)hipFuncSetAttribute((const void*)VanillaRNN_70025146794452_kernel,
                              hipFuncAttributeMaxDynamicSharedMemorySize, SMEM_TOTAL);
    rnn_u_precompute<<<dim3(NBLK, T_SEQ / TTP), dim3(512), 0, stream>>>(x, Whx, bh, U);
    VanillaRNN_70025146794452_kernel<<<dim3(NBLK), dim3(512), SMEM_TOTAL, stream>>>(
        Whh, Wph, bp, U, out);
  } else {
    (void)hipFuncSetAttribute((const void*)rnn_fallback_kernel,
                              hipFuncAttributeMaxDynamicSharedMemorySize, FB_SMEM);
    rnn_fallback_kernel<<<dim3(NBLK), dim3(512), FB_SMEM, stream>>>(
        x, Whx, Whh, Wph, bh, bp, out);
  }
}

// Round 5
// 1841.410 us; speedup vs baseline: 1.2884x; 1.0035x over previous
//
#include <hip/hip_runtime.h>
#include <hip/hip_bf16.h>
#include <hip/hip_fp8.h>
#include <cstdint>
#include <cstddef>

// VanillaRNN: h_{t+1} = tanh(x_t @ Whx + h_t @ Whh + bh), p = h_T @ Wph + bp
// B=256, T=1024, D=64, H=512, C=10.
//
// R13 = R12 (1666us consumer / 1848us total) + MX-scale fp8 for h[320,448):
//  - one mfma_scale_f32_16x16x128_f8f6f4 per n-tile (scale=2^0 => products
//    bit-identical to plain fp8 MFMA) replaces 4x K=32 fp8 steps: fp8-region
//    MFMA time 620 -> 276 CU-cyc/step.
//  - all fp8 weights now register-resident (MX 32 VGPR + tail 16 VGPR); the
//    64KB LDS weight buffer and its 8 ds_read_b128/wave/step are GONE.
// Session lessons (R9/R10/R11 regressed; do not retry): cross-CU per-step
// exchange dead (3us/step); intra-block flag gating kills ds_read->MFMA
// pipelining (BB boundaries force lgkmcnt drains). Keep ONE __syncthreads
// per step + straight-line K-loop.
// Fallback (ws < 256MiB): R2 kernel verbatim.

#define T_SEQ   1024
#define D_IN    64
#define H_DIM   512
#define NB      16
#define NBLK    16
#define NTW     4            // N-tiles (16 cols) per wave; wave owns 64 cols
#define KS_F16  10           // f16 K-steps: h[0,320)
#define KS_TL8  2            // fp8 K=32 tail steps: h[448,512)
#define HSPLIT  320          // h cols >= HSPLIT stored fp8
#define APITCH  848          // bytes per A row: 640 f16 + 192 fp8 + 16 pad
#define FP8OFF  640
#define ABUF_BYTES (2 * NB * APITCH)              // 27136
#define SMEM_TOTAL ABUF_BYTES                     // no LDS weights anymore
#define WSCALE  256.0f
#define HSCALE  128.0f
#define UNSCALE (1.0f / 32768.0f)
#define U_BYTES ((size_t)T_SEQ * NBLK * 512 * 32) // 268435456 (f16 U, all t)
#define TTP     64           // t-steps per precompute block (grid 16x16)

typedef __attribute__((ext_vector_type(8))) short  short8;
typedef __attribute__((ext_vector_type(4))) short  short4v;
typedef __attribute__((ext_vector_type(4))) float  f32x4;
typedef __attribute__((ext_vector_type(4))) unsigned int uint4v;
typedef __attribute__((ext_vector_type(2))) unsigned int uint2v;
typedef __attribute__((ext_vector_type(8))) int    int8v;

#if defined(__has_builtin)
#if __has_builtin(__builtin_amdgcn_mfma_scale_f32_16x16x128_f8f6f4)
#define HAVE_MX 1
#endif
#endif
#ifndef HAVE_MX
#define HAVE_MX 0
#endif

static __device__ __forceinline__ short f16b(float v) {
  return __builtin_bit_cast(short, (_Float16)v);
}
static __device__ __forceinline__ short bf16b(float v) {
  return __builtin_bit_cast(short, __float2bfloat16(v));
}
static __device__ __forceinline__ float f16f(unsigned short u) {
  return (float)__builtin_bit_cast(_Float16, (short)u);
}
static __device__ __forceinline__ unsigned int pk2h(float a, float b) {
#if defined(__has_builtin) && __has_builtin(__builtin_amdgcn_cvt_pkrtz)
  return __builtin_bit_cast(unsigned int, __builtin_amdgcn_cvt_pkrtz(a, b));
#else
  return (unsigned int)(unsigned short)f16b(a) |
         ((unsigned int)(unsigned short)f16b(b) << 16);
#endif
}
// tanh(x) = 1 - 2/(e^{2x}+1); exp2 overflow/underflow saturate to +-1 exactly,
// so no clamp is needed. 5 VALU ops.
static __device__ __forceinline__ float fast_tanh(float x) {
  const float t = __builtin_amdgcn_exp2f(x * 2.885390081777927f); // 2*log2(e)
  return 1.f - 2.f * __builtin_amdgcn_rcpf(t + 1.f);
}
static __device__ __forceinline__ unsigned char f32_to_fp8(float v) {
#if defined(__has_builtin) && __has_builtin(__builtin_amdgcn_cvt_pk_fp8_f32)
  const int r = __builtin_amdgcn_cvt_pk_fp8_f32(v, v, 0, false);
  return (unsigned char)(r & 0xff);
#else
  __hip_fp8_e4m3 f(v);
  return (unsigned char)f.__x;
#endif
}
static __device__ __forceinline__ unsigned int pk4fp8(float a, float b, float c, float d) {
#if defined(__has_builtin) && __has_builtin(__builtin_amdgcn_cvt_pk_fp8_f32)
  int r = __builtin_amdgcn_cvt_pk_fp8_f32(a, b, 0, false);
  r = __builtin_amdgcn_cvt_pk_fp8_f32(c, d, r, true);
  return (unsigned int)r;
#else
  return (unsigned int)f32_to_fp8(a) | ((unsigned int)f32_to_fp8(b) << 8) |
         ((unsigned int)f32_to_fp8(c) << 16) | ((unsigned int)f32_to_fp8(d) << 24);
#endif
}
static __device__ __forceinline__ float fp8_to_f32(unsigned char b) {
  __hip_fp8_e4m3 f;
  f.__x = (__hip_fp8_storage_t)b;
  return (float)f;
}

// ============================ precompute: U = x@Whx + bh =====================
__global__ __launch_bounds__(512, 2)
void rnn_u_precompute(const float* __restrict__ x, const float* __restrict__ Whx,
                      const float* __restrict__ bh, char* __restrict__ U)
{
  const int tid  = threadIdx.x;
  const int lane = tid & 63;
  const int w    = tid >> 6;
  const int n16  = lane & 15;
  const int kq   = lane >> 4;
  const int wg   = blockIdx.x;
  const int cwave = w * 64;

  short8 wa[2][NTW];
  #pragma unroll
  for (int s = 0; s < 2; ++s) {
    #pragma unroll
    for (int nt = 0; nt < NTW; ++nt) {
      const int c = cwave + nt * 16 + n16;
      short8 f;
      #pragma unroll
      for (int j = 0; j < 8; ++j)
        f[j] = f16b(Whx[(size_t)(s * 32 + kq * 8 + j) * H_DIM + c]);
      wa[s][nt] = f;
    }
  }
  f32x4 bb[NTW];
  #pragma unroll
  for (int nt = 0; nt < NTW; ++nt) {
    #pragma unroll
    for (int i = 0; i < 4; ++i) bb[nt][i] = bh[cwave + nt * 16 + kq * 4 + i];
  }

  const int b = wg * NB + n16;
  const float* pxb = x + (size_t)b * T_SEQ * D_IN + kq * 8;
  const int t0 = blockIdx.y * TTP;

  f32x4 c0, c1, c2, c3;
  {
    const float* p = pxb + (size_t)t0 * D_IN;
    c0 = *(const f32x4*)p;        c1 = *(const f32x4*)(p + 4);
    c2 = *(const f32x4*)(p + 32); c3 = *(const f32x4*)(p + 36);
  }

  for (int tt = 0; tt < TTP; ++tt) {
    const int t = t0 + tt;
    f32x4 n0, n1, n2, n3;
    if (tt + 1 < TTP) {
      const float* p = pxb + (size_t)(t + 1) * D_IN;
      n0 = *(const f32x4*)p;        n1 = *(const f32x4*)(p + 4);
      n2 = *(const f32x4*)(p + 32); n3 = *(const f32x4*)(p + 36);
    }
    short8 xb0, xb1;
    xb0[0]=f16b(c0.x); xb0[1]=f16b(c0.y); xb0[2]=f16b(c0.z); xb0[3]=f16b(c0.w);
    xb0[4]=f16b(c1.x); xb0[5]=f16b(c1.y); xb0[6]=f16b(c1.z); xb0[7]=f16b(c1.w);
    xb1[0]=f16b(c2.x); xb1[1]=f16b(c2.y); xb1[2]=f16b(c2.z); xb1[3]=f16b(c2.w);
    xb1[4]=f16b(c3.x); xb1[5]=f16b(c3.y); xb1[6]=f16b(c3.z); xb1[7]=f16b(c3.w);

    f32x4 D[NTW];
    #pragma unroll
    for (int nt = 0; nt < NTW; ++nt) {
      D[nt] = bb[nt];
      D[nt] = __builtin_amdgcn_mfma_f32_16x16x32_f16(wa[0][nt], xb0, D[nt], 0, 0, 0);
      D[nt] = __builtin_amdgcn_mfma_f32_16x16x32_f16(wa[1][nt], xb1, D[nt], 0, 0, 0);
    }
    uint4v o0, o1;
    o0.x = pk2h(D[0][0], D[0][1]); o0.y = pk2h(D[0][2], D[0][3]);
    o0.z = pk2h(D[1][0], D[1][1]); o0.w = pk2h(D[1][2], D[1][3]);
    o1.x = pk2h(D[2][0], D[2][1]); o1.y = pk2h(D[2][2], D[2][3]);
    o1.z = pk2h(D[3][0], D[3][1]); o1.w = pk2h(D[3][2], D[3][3]);
    char* dst = U + (((size_t)t * NBLK + wg) * 512 + tid) * 32;
    *(uint4v*)dst = o0;
    *(uint4v*)(dst + 16) = o1;

    c0 = n0; c1 = n1; c2 = n2; c3 = n3;
  }
}

// ============================ main recurrence (R8 structure + MX tail) =======
__global__ __launch_bounds__(512, 2)
void VanillaRNN_70025146794452_kernel(
    const float* __restrict__ Whh,  // [512][512]
    const float* __restrict__ Wph,  // [512][10]
    const float* __restrict__ bp,   // [10]
    const char* __restrict__ U,     // precomputed, swizzled f16
    float* __restrict__ out)        // [256][10]
{
  const int tid  = threadIdx.x;
  const int lane = tid & 63;
  const int w    = tid >> 6;
  const int n16  = lane & 15;
  const int kq   = lane >> 4;
  const int rbase = blockIdx.x * NB;
  const int cwave = w * 64;

  extern __shared__ char smem[];
  char* Ab = smem;                                  // [2][NB][APITCH]

  // -------- preload: f16 weight A-frags (h-k in [0,320)), 40 frags
  short8 wr[KS_F16][NTW];
  #pragma unroll
  for (int s = 0; s < KS_F16; ++s) {
    #pragma unroll
    for (int nt = 0; nt < NTW; ++nt) {
      const int c = cwave + nt * 16 + n16;
      short8 f;
      #pragma unroll
      for (int j = 0; j < 8; ++j)
        f[j] = f16b(Whh[(size_t)(s * 32 + kq * 8 + j) * H_DIM + c]);
      wr[s][nt] = f;
    }
  }

#if HAVE_MX
  // -------- preload: MX fp8 A-frags, h-k in [320,448): lane holds
  // Whh[320 + kq*32 + j][c], j=0..31 -> 8 dwords (byte j of block = k+j).
  int8v wmx[NTW];
  #pragma unroll
  for (int nt = 0; nt < NTW; ++nt) {
    const int c = cwave + nt * 16 + n16;
    int8v v;
    #pragma unroll
    for (int d = 0; d < 8; ++d) {
      unsigned acc = 0;
      #pragma unroll
      for (int bi = 0; bi < 4; ++bi) {
        const int k = HSPLIT + kq * 32 + d * 4 + bi;
        acc |= ((unsigned)f32_to_fp8(Whh[(size_t)k * H_DIM + c] * WSCALE)) << (8 * bi);
      }
      v[d] = (int)acc;
    }
    wmx[nt] = v;
  }
  // -------- preload: tail fp8 reg A-frags, h-k in [448,512)
  long long wt8[KS_TL8][NTW];
  #pragma unroll
  for (int s = 0; s < KS_TL8; ++s) {
    #pragma unroll
    for (int nt = 0; nt < NTW; ++nt) {
      const int c  = cwave + nt * 16 + n16;
      const int k0 = HSPLIT + 128 + s * 32 + kq * 8;
      unsigned lo = 0, hi = 0;
      #pragma unroll
      for (int bi = 0; bi < 4; ++bi) {
        lo |= ((unsigned)f32_to_fp8(Whh[(size_t)(k0 + bi) * H_DIM + c] * WSCALE)) << (8 * bi);
        hi |= ((unsigned)f32_to_fp8(Whh[(size_t)(k0 + 4 + bi) * H_DIM + c] * WSCALE)) << (8 * bi);
      }
      wt8[s][nt] = (long long)(((unsigned long long)hi << 32) | lo);
    }
  }
#else
  // no MX builtin: all 6 fp8 K=32 steps with reg weights
  long long wt8[6][NTW];
  #pragma unroll
  for (int s = 0; s < 6; ++s) {
    #pragma unroll
    for (int nt = 0; nt < NTW; ++nt) {
      const int c  = cwave + nt * 16 + n16;
      const int k0 = HSPLIT + s * 32 + kq * 8;
      unsigned lo = 0, hi = 0;
      #pragma unroll
      for (int bi = 0; bi < 4; ++bi) {
        lo |= ((unsigned)f32_to_fp8(Whh[(size_t)(k0 + bi) * H_DIM + c] * WSCALE)) << (8 * bi);
        hi |= ((unsigned)f32_to_fp8(Whh[(size_t)(k0 + 4 + bi) * H_DIM + c] * WSCALE)) << (8 * bi);
      }
      wt8[s][nt] = (long long)(((unsigned long long)hi << 32) | lo);
    }
  }
#endif

  // -------- prologue: zero both A buffers (h_0 = 0), prefetch U(t=0)
  for (int i = tid; i < ABUF_BYTES / 4; i += 512) ((int*)Ab)[i] = 0;
  uint4v Upf0, Upf1;
  {
    const char* up = U + (((size_t)0 * NBLK + blockIdx.x) * 512 + tid) * 32;
    Upf0 = *(const uint4v*)up;
    Upf1 = *(const uint4v*)(up + 16);
  }

  f32x4 C[NTW], C2[NTW];

  // -------- main recurrence (C || C2 chains, fold at epilogue)
  for (int t = 0; t < T_SEQ; ++t) {
    __syncthreads();
    char* Ac = Ab + (t & 1) * (NB * APITCH);
    char* An = Ab + ((t + 1) & 1) * (NB * APITCH);

    short8 hb = *(const short8*)(Ac + n16 * APITCH + 0 * 64 + kq * 16);

    // C-init from prefetched U
    C[0][0]=f16f(Upf0.x&0xffff); C[0][1]=f16f(Upf0.x>>16);
    C[0][2]=f16f(Upf0.y&0xffff); C[0][3]=f16f(Upf0.y>>16);
    C[1][0]=f16f(Upf0.z&0xffff); C[1][1]=f16f(Upf0.z>>16);
    C[1][2]=f16f(Upf0.w&0xffff); C[1][3]=f16f(Upf0.w>>16);
    C[2][0]=f16f(Upf1.x&0xffff); C[2][1]=f16f(Upf1.x>>16);
    C[2][2]=f16f(Upf1.y&0xffff); C[2][3]=f16f(Upf1.y>>16);
    C[3][0]=f16f(Upf1.z&0xffff); C[3][1]=f16f(Upf1.z>>16);
    C[3][2]=f16f(Upf1.w&0xffff); C[3][3]=f16f(Upf1.w>>16);
    #pragma unroll
    for (int nt = 0; nt < NTW; ++nt) C2[nt] = (f32x4){0.f, 0.f, 0.f, 0.f};

    // prefetch U(t+1)
    {
      const int t1 = (t + 1 < T_SEQ) ? (t + 1) : (T_SEQ - 1);
      const char* up = U + (((size_t)t1 * NBLK + blockIdx.x) * 512 + tid) * 32;
      Upf0 = *(const uint4v*)up;
      Upf1 = *(const uint4v*)(up + 16);
    }

    // f16 phase (C-chain)
    #pragma unroll
    for (int s = 0; s < KS_F16; ++s) {
      const short8 a = hb;
      if (s + 1 < KS_F16)
        hb = *(const short8*)(Ac + n16 * APITCH + (s + 1) * 64 + kq * 16);
      #pragma unroll
      for (int nt = 0; nt < NTW; ++nt)
        C[nt] = __builtin_amdgcn_mfma_f32_16x16x32_f16(wr[s][nt], a, C[nt], 0, 0, 0);
    }

#if HAVE_MX
    // fp8 MX phase: one K=128 scaled MFMA per n-tile (scale = 2^0 -> products
    // identical to plain fp8). B: 32 contiguous fp8 of row n16 at kq*32.
    {
      const char* hp = Ac + n16 * APITCH + FP8OFF + kq * 32;
      const uint4v m0 = *(const uint4v*)hp;
      const uint4v m1 = *(const uint4v*)(hp + 16);
      int8v hmx;
      hmx[0]=(int)m0.x; hmx[1]=(int)m0.y; hmx[2]=(int)m0.z; hmx[3]=(int)m0.w;
      hmx[4]=(int)m1.x; hmx[5]=(int)m1.y; hmx[6]=(int)m1.z; hmx[7]=(int)m1.w;
      #pragma unroll
      for (int nt = 0; nt < NTW; ++nt)
        C2[nt] = __builtin_amdgcn_mfma_scale_f32_16x16x128_f8f6f4(
            wmx[nt], hmx, C2[nt], 0, 0, 0, 0x7F7F7F7F, 0, 0x7F7F7F7F);
    }
    // fp8 tail: h[448,512), 2x K=32 with reg weights
    #pragma unroll
    for (int s = 0; s < KS_TL8; ++s) {
      const long long h8 = *(const long long*)(Ac + n16 * APITCH + FP8OFF + 128 + s * 32 + kq * 8);
      #pragma unroll
      for (int nt = 0; nt < NTW; ++nt)
        C2[nt] = __builtin_amdgcn_mfma_f32_16x16x32_fp8_fp8(wt8[s][nt], h8, C2[nt], 0, 0, 0);
    }
#else
    #pragma unroll
    for (int s = 0; s < 6; ++s) {
      const long long h8 = *(const long long*)(Ac + n16 * APITCH + FP8OFF + s * 32 + kq * 8);
      #pragma unroll
      for (int nt = 0; nt < NTW; ++nt)
        C2[nt] = __builtin_amdgcn_mfma_f32_16x16x32_fp8_fp8(wt8[s][nt], h8, C2[nt], 0, 0, 0);
    }
#endif

    // epilogue: fold + tanh + packed store (D transposed: row n16 = batch,
    // reg i = col kq*4+i)
    char* drow = An + n16 * APITCH;
    if (cwave < HSPLIT) {            // waves 0..4: f16 region
      #pragma unroll
      for (int nt = 0; nt < NTW; ++nt) {
        const int c0 = cwave + nt * 16 + kq * 4;
        float v0 = fast_tanh(fmaf(C2[nt][0], UNSCALE, C[nt][0]));
        float v1 = fast_tanh(fmaf(C2[nt][1], UNSCALE, C[nt][1]));
        float v2 = fast_tanh(fmaf(C2[nt][2], UNSCALE, C[nt][2]));
        float v3 = fast_tanh(fmaf(C2[nt][3], UNSCALE, C[nt][3]));
        uint2v o; o.x = pk2h(v0, v1); o.y = pk2h(v2, v3);
        *(uint2v*)(drow + c0 * 2) = o;
      }
    } else {                          // waves 5..7: fp8 region
      #pragma unroll
      for (int nt = 0; nt < NTW; ++nt) {
        const int c0 = cwave + nt * 16 + kq * 4;
        float v0 = fast_tanh(fmaf(C2[nt][0], UNSCALE, C[nt][0]));
        float v1 = fast_tanh(fmaf(C2[nt][1], UNSCALE, C[nt][1]));
        float v2 = fast_tanh(fmaf(C2[nt][2], UNSCALE, C[nt][2]));
        float v3 = fast_tanh(fmaf(C2[nt][3], UNSCALE, C[nt][3]));
        *(unsigned int*)(drow + FP8OFF + (c0 - HSPLIT)) =
            pk4fp8(v0 * HSCALE, v1 * HSCALE, v2 * HSCALE, v3 * HSCALE);
      }
    }
  }

  __syncthreads();
  // h_T in buffer 0 (T even). Projection: 16 rows x 10 classes per block.
  if (tid < NB * 10) {
    const int r = tid / 10, c = tid % 10;
    const char* row = Ab + r * APITCH;
    float acc = bp[c];
    #pragma unroll 8
    for (int k = 0; k < HSPLIT; ++k)
      acc += f16f(*(const unsigned short*)(row + k * 2)) * Wph[k * 10 + c];
    #pragma unroll 8
    for (int k = HSPLIT; k < H_DIM; ++k)
      acc += fp8_to_f32((unsigned char)row[FP8OFF + (k - HSPLIT)]) * (1.f / HSCALE) * Wph[k * 10 + c];
    out[(size_t)(rbase + r) * 10 + c] = acc;
  }
}

// ============================ fallback (R2 verbatim, 2833us) =================
#define FB_APITCH  1040
#define FB_FP8OFF  768
#define FB_ABUF    (2 * NB * FB_APITCH)
#define FB_WWAVE   (6 * 2 * 1024)
#define FB_SMEM    (FB_ABUF + 8 * FB_WWAVE)       // 131584

__global__ __launch_bounds__(512, 2)
void rnn_fallback_kernel(
    const float* __restrict__ x, const float* __restrict__ Whx,
    const float* __restrict__ Whh, const float* __restrict__ Wph,
    const float* __restrict__ bh, const float* __restrict__ bp,
    float* __restrict__ out)
{
  const int tid = threadIdx.x, lane = tid & 63, w = tid >> 6;
  const int n16 = lane & 15, kq = lane >> 4;
  const int rbase = blockIdx.x * NB, cwave = w * 64;
  extern __shared__ char smem[];
  char* Ab  = smem;
  char* Wlw = smem + FB_ABUF + w * FB_WWAVE;

  short8 wr[12 * 4];
  #pragma unroll
  for (int s = 0; s < 12; ++s)
    #pragma unroll
    for (int nt = 0; nt < 4; ++nt) {
      const int c = cwave + nt * 16 + n16, k0 = s * 32 + kq * 8;
      short8 f;
      #pragma unroll
      for (int j = 0; j < 8; ++j) {
        const int k = k0 + j;
        const float* src = (k < D_IN) ? (Whx + (size_t)k * H_DIM + c)
                                      : (Whh + (size_t)(k - D_IN) * H_DIM + c);
        f[j] = bf16b(*src);
      }
      wr[s * 4 + nt] = f;
    }
  for (int s = 0; s < 6; ++s)
    for (int pp = 0; pp < 2; ++pp) {
      const int k0 = (12 + s) * 32 + kq * 8;
      unsigned int bq[4];
      #pragma unroll
      for (int half = 0; half < 2; ++half) {
        const int c = cwave + (2 * pp + half) * 16 + n16;
        #pragma unroll
        for (int u = 0; u < 2; ++u) {
          unsigned int acc = 0;
          #pragma unroll
          for (int bi = 0; bi < 4; ++bi)
            acc |= ((unsigned int)f32_to_fp8(Whh[(size_t)(k0 + u * 4 + bi - D_IN) * H_DIM + c] * WSCALE)) << (8 * bi);
          bq[half * 2 + u] = acc;
        }
      }
      uint4v pk; pk.x = bq[0]; pk.y = bq[1]; pk.z = bq[2]; pk.w = bq[3];
      *(uint4v*)(Wlw + (size_t)(s * 2 + pp) * 1024 + lane * 16) = pk;
    }
  float bhreg[4];
  #pragma unroll
  for (int nt = 0; nt < 4; ++nt) bhreg[nt] = bh[cwave + nt * 16 + n16];
  for (int i = tid; i < FB_ABUF / 4; i += 512) ((int*)Ab)[i] = 0;
  const int xr = (tid >> 4) & 15, xc4 = (tid & 15) * 4;
  if (tid < 256) {
    const f32x4 xv = *(const f32x4*)(x + ((size_t)(rbase + xr) * T_SEQ) * D_IN + xc4);
    short4v s4; s4[0]=bf16b(xv.x); s4[1]=bf16b(xv.y); s4[2]=bf16b(xv.z); s4[3]=bf16b(xv.w);
    *(short4v*)(Ab + xr * FB_APITCH + xc4 * 2) = s4;
  }
  f32x4 C[4], C2[4];
  for (int t = 0; t < T_SEQ; ++t) {
    __syncthreads();
    char* Ac = Ab + (t & 1) * (NB * FB_APITCH);
    char* An = Ab + ((t + 1) & 1) * (NB * FB_APITCH);
    const int t1 = (t + 1 < T_SEQ) ? (t + 1) : (T_SEQ - 1);
    f32x4 xv;
    if (tid < 256)
      xv = *(const f32x4*)(x + ((size_t)(rbase + xr) * T_SEQ + t1) * D_IN + xc4);
    #pragma unroll
    for (int nt = 0; nt < 4; ++nt) {
      C[nt] = (f32x4){0.f,0.f,0.f,0.f}; C2[nt] = (f32x4){0.f,0.f,0.f,0.f};
    }
    #pragma unroll
    for (int s = 0; s < 12; ++s) {
      const short8 a = *(const short8*)(Ac + n16 * FB_APITCH + s * 64 + kq * 16);
      #pragma unroll
      for (int nt = 0; nt < 4; ++nt)
        C[nt] = __builtin_amdgcn_mfma_f32_16x16x32_bf16(a, wr[s * 4 + nt], C[nt], 0, 0, 0);
    }
    #pragma unroll
    for (int s = 0; s < 6; ++s) {
      const long long a8 = *(const long long*)(Ac + n16 * FB_APITCH + FB_FP8OFF + s * 32 + kq * 8);
      #pragma unroll
      for (int pp = 0; pp < 2; ++pp) {
        const uint4v q = *(const uint4v*)(Wlw + (size_t)(s * 2 + pp) * 1024 + lane * 16);
        const long long b0 = (long long)(((unsigned long long)q.y << 32) | q.x);
        const long long b1 = (long long)(((unsigned long long)q.w << 32) | q.z);
        C2[2*pp]   = __builtin_amdgcn_mfma_f32_16x16x32_fp8_fp8(a8, b0, C2[2*pp],   0, 0, 0);
        C2[2*pp+1] = __builtin_amdgcn_mfma_f32_16x16x32_fp8_fp8(a8, b1, C2[2*pp+1], 0, 0, 0);
      }
    }
    if (tid < 256) {
      short4v s4; s4[0]=bf16b(xv.x); s4[1]=bf16b(xv.y); s4[2]=bf16b(xv.z); s4[3]=bf16b(xv.w);
      *(short4v*)(An + xr * FB_APITCH + xc4 * 2) = s4;
    }
    const int row0 = kq * 4;
    #pragma unroll
    for (int nt = 0; nt < 4; ++nt) {
      const int cbase = cwave + nt * 16;
      #pragma unroll
      for (int i = 0; i < 4; ++i) {
        const float v = fast_tanh(fmaf(C2[nt][i], UNSCALE, C[nt][i]) + bhreg[nt]);
        char* dst = An + (row0 + i) * FB_APITCH;
        if (cbase < 320) *(short*)(dst + 128 + (cbase + n16) * 2) = bf16b(v);
        else dst[FB_FP8OFF + (cbase + n16 - 320)] = f32_to_fp8(v * HSCALE);
      }
    }
  }
  __syncthreads();
  if (tid < NB * 10) {
    const int r = tid / 10, c = tid % 10;
    const char* row = Ab + r * FB_APITCH;
    float acc = bp[c];
    #pragma unroll 8
    for (int k = 0; k < 320; ++k) {
      const __hip_bfloat16 hb = __builtin_bit_cast(__hip_bfloat16, *(const short*)(row + 128 + k * 2));
      acc += __bfloat162float(hb) * Wph[k * 10 + c];
    }
    #pragma unroll 8
    for (int k = 320; k < H_DIM; ++k)
      acc += fp8_to_f32((unsigned char)row[FB_FP8OFF + (k - 320)]) * (1.f / HSCALE) * Wph[k * 10 + c];
    out[(size_t)(rbase + r) * 10 + c] = acc;
  }
}

extern "C" void kernel_launch(void* const* d_in, const int* in_sizes, int n_in,
                              void* d_out, int out_size, void* d_ws, size_t ws_size,
                              hipStream_t stream) {
  const float* x   = (const float*)d_in[0];
  const float* Whx = (const float*)d_in[1];
  const float* Whh = (const float*)d_in[2];
  const float* Wph = (const float*)d_in[3];
  const float* bh  = (const float*)d_in[4];
  const float* bp  = (const float*)d_in[5];
  float* out = (float*)d_out;

  if (ws_size >= U_BYTES) {
    char* U = (char*)d_ws;
    (void)hipFuncSetAttribute((const void*)VanillaRNN_70025146794452_kernel,
                              hipFuncAttributeMaxDynamicSharedMemorySize, SMEM_TOTAL);
    rnn_u_precompute<<<dim3(NBLK, T_SEQ / TTP), dim3(512), 0, stream>>>(x, Whx, bh, U);
    VanillaRNN_70025146794452_kernel<<<dim3(NBLK), dim3(512), SMEM_TOTAL, stream>>>(
        Whh, Wph, bp, U, out);
  } else {
    (void)hipFuncSetAttribute((const void*)rnn_fallback_kernel,
                              hipFuncAttributeMaxDynamicSharedMemorySize, FB_SMEM);
    rnn_fallback_kernel<<<dim3(NBLK), dim3(512), FB_SMEM, stream>>>(
        x, Whx, Whh, Wph, bh, bp, out);
  }
}